// Round 3
// baseline (72.189 us; speedup 1.0000x reference)
//
#include <hip/hip_runtime.h>

// Exponential smoothing: s[-1]=v0; s[j] = w*s[j-1] + (1-w)*x[j]; out[j]=s[j]
// w = sigmoid(smoothing_weight[h]).
// 2-kernel chunked scan:
//   K1: per (b,chunk) compute chunk-local end state (zero init) -> agg (4 MiB)
//   K2: per (b,chunk) recompute entering carry from agg[0..c) (L2-resident),
//       rescan chunk seeded with carry, write out.
// Kernel boundary provides the cross-XCD visibility for agg (no lookback spin).

namespace {

constexpr int Bt = 16;     // batch
constexpr int Tt = 4096;   // time
constexpr int HD = 512;    // h*d channels, contiguous at fixed (b,t)
constexpr int HD4 = HD / 4;   // float4 channels = 128 = blockDim
constexpr int CL = 32;        // chunk length along t
constexpr int NC = Tt / CL;   // 128 chunks

__device__ __forceinline__ float sigmoidf_(float x) {
    return 1.0f / (1.0f + expf(-x));
}

// K1: chunk-local scan end state with zero initial state.
__global__ __launch_bounds__(HD4) void ema_k1(
    const float4* __restrict__ values4, const float* __restrict__ sw,
    float4* __restrict__ agg4) {
    const int blk = blockIdx.x;
    const int b = blk & (Bt - 1);
    const int c = blk >> 4;
    const int t4 = threadIdx.x;               // float4-channel index
    const float w = sigmoidf_(sw[t4 >> 4]);   // h = (4*t4)>>6 = t4>>4
    const float omw = 1.0f - w;

    const float4* p = values4 + ((size_t)b * Tt + (size_t)c * CL) * HD4 + t4;
    float4 s = make_float4(0.f, 0.f, 0.f, 0.f);
    for (int j0 = 0; j0 < CL; j0 += 8) {
        float4 x[8];
        #pragma unroll
        for (int u = 0; u < 8; ++u) x[u] = p[(size_t)(j0 + u) * HD4];
        #pragma unroll
        for (int u = 0; u < 8; ++u) {
            s.x = fmaf(w, s.x, omw * x[u].x);
            s.y = fmaf(w, s.y, omw * x[u].y);
            s.z = fmaf(w, s.z, omw * x[u].z);
            s.w = fmaf(w, s.w, omw * x[u].w);
        }
    }
    agg4[((size_t)c * Bt + b) * HD4 + t4] = s;
}

// K2: recompute carry from aggregates, rescan chunk, write out.
__global__ __launch_bounds__(HD4) void ema_k2(
    const float4* __restrict__ values4, const float* __restrict__ sw,
    const float4* __restrict__ v04, const float4* __restrict__ agg4,
    float4* __restrict__ out4) {
    const int blk = blockIdx.x;
    const int b = blk & (Bt - 1);
    const int c = blk >> 4;
    const int t4 = threadIdx.x;
    const float w = sigmoidf_(sw[t4 >> 4]);
    const float omw = 1.0f - w;

    // Wc = w^CL (CL = 32): 5 squarings
    float Wc = w;
    #pragma unroll
    for (int i = 0; i < 5; ++i) Wc *= Wc;

    // carry = state entering chunk c: s = v0; for k<c: s = Wc*s + A_k
    float4 s = v04[t4];
    const float4* a = agg4 + b * HD4 + t4;
    for (int k = 0; k < c; ++k) {
        float4 A = a[(size_t)k * Bt * HD4];
        s.x = fmaf(Wc, s.x, A.x);
        s.y = fmaf(Wc, s.y, A.y);
        s.z = fmaf(Wc, s.z, A.z);
        s.w = fmaf(Wc, s.w, A.w);
    }

    const size_t base = ((size_t)b * Tt + (size_t)c * CL) * HD4 + t4;
    const float4* p = values4 + base;
    float4* q = out4 + base;
    for (int j0 = 0; j0 < CL; j0 += 8) {
        float4 x[8];
        #pragma unroll
        for (int u = 0; u < 8; ++u) x[u] = p[(size_t)(j0 + u) * HD4];
        #pragma unroll
        for (int u = 0; u < 8; ++u) {
            s.x = fmaf(w, s.x, omw * x[u].x);
            s.y = fmaf(w, s.y, omw * x[u].y);
            s.z = fmaf(w, s.z, omw * x[u].z);
            s.w = fmaf(w, s.w, omw * x[u].w);
            q[(size_t)(j0 + u) * HD4] = s;
        }
    }
}

}  // namespace

extern "C" void kernel_launch(void* const* d_in, const int* in_sizes, int n_in,
                              void* d_out, int out_size, void* d_ws, size_t ws_size,
                              hipStream_t stream) {
    const float4* values4 = (const float4*)d_in[0];  // [16, 4096, 8, 64] f32
    const float* sw       = (const float*)d_in[1];   // [8, 1]
    const float4* v04     = (const float4*)d_in[2];  // [1, 1, 8, 64]
    float4* out4 = (float4*)d_out;

    float4* agg4 = (float4*)d_ws;  // NC*Bt*HD floats = 4 MiB

    ema_k1<<<dim3(NC * Bt), dim3(HD4), 0, stream>>>(values4, sw, agg4);
    ema_k2<<<dim3(NC * Bt), dim3(HD4), 0, stream>>>(values4, sw, v04, agg4, out4);
}